// Round 19
// baseline (146.220 us; speedup 1.0000x reference)
//
#include <hip/hip_runtime.h>
#include <math.h>

#define NG 8
#define SEQ 4096
#define DM 1024
#define NE 64
#define GS (NG * SEQ)          // 32768 tokens
#define KSEL 1024              // expert capacity
#define MASK_ELEMS (NE * GS)   // 2097152
#define SEG 16
#define SEGLEN (GS / SEG)
#define CAP 2048               // max repair candidates per expert
#define CAP2 16384             // max compacted entries per expert

typedef __attribute__((ext_vector_type(8))) short short8;
typedef __attribute__((ext_vector_type(4))) float f32x4;

__device__ __forceinline__ unsigned short f2bf(float v) {   // RN-even
  unsigned u = __float_as_uint(v);
  return (unsigned short)((u + 0x7FFFu + ((u >> 16) & 1u)) >> 16);
}
__device__ __forceinline__ float bf2f(unsigned short h) {
  return __uint_as_float(((unsigned)h) << 16);
}

// ---------------- Kernel 0: weight split (wave-fragment order) + counter zeroing --
__global__ __launch_bounds__(256)
void k_split(const float* __restrict__ w, unsigned short* __restrict__ wph,
             unsigned short* __restrict__ wpm, unsigned* __restrict__ zbase) {
  const int t = blockIdx.x * 256 + threadIdx.x;
  if (t < NE * 256 + NE) zbase[t] = 0u;
  const int k = t >> 6, e = t & 63;
  float v = w[t];
  unsigned short h = f2bf(v); float r = v - bf2f(h);
  const int tile = k >> 5, g = (k >> 3) & 3, j = k & 7;
  const int cb = e >> 4, lrow = e & 15;
  const size_t o = (size_t)(tile * 4 + cb) * 512 + (g * 16 + lrow) * 8 + j;
  wph[o] = h; wpm[o] = f2bf(r);
}

// ---------------- Kernel 1: bf16x2 MFMA GEMM, B shared via LDS (4 waves/block) ----
// Round-18 diagnosis: every wave privately streaming the 512KB B planes (8192
// waves x ~80 loads) = latency exposure under L2/L3 contention; wall ~77us even
// with x L3-resident. Fix: block of 4 waves shares B through double-buffered LDS
// (16KB/iter staged cooperatively, T14 async order), waves = 2 token-groups x
// 2 K-halves; A direct per-lane global with 2-tile register prefetch.
__global__ __launch_bounds__(256, 3)
void k_gemm_softmax(const float* __restrict__ x,
                    const unsigned short* __restrict__ wph,
                    const unsigned short* __restrict__ wpm,
                    const float* __restrict__ bias, const float* __restrict__ temp,
                    float* __restrict__ probsT) {
  __shared__ __align__(16) unsigned char Bs[2][16384];   // 32 KB dbuf
  __shared__ float Lt[4][16][68];                        // 17.4 KB
  float (*Pt)[36] = (float (*)[36])&Bs[0][0];            // overlay after K-loop

  const int tid = threadIdx.x;
  const int w = tid >> 6, lane = tid & 63;
  const int tg = w >> 1, kh = w & 1;     // token-group, K-half
  const int lrow = lane & 15, g = lane >> 4;
  const int m0 = blockIdx.x * 32 + tg * 16;

  // --- probes: C/D (lane,reg)->(i,j) for mfma_f32_16x16x32_bf16 (exact ints) ---
  int irow[4], jcol[4];
  {
    union { unsigned short u[8]; short8 v; } ar, on;
#pragma unroll
    for (int j = 0; j < 8; ++j) { ar.u[j] = f2bf((float)lrow); on.u[j] = 0x3F80u; }
    f32x4 z = {0.f, 0.f, 0.f, 0.f};
    f32x4 p1 = __builtin_amdgcn_mfma_f32_16x16x32_bf16(ar.v, on.v, z, 0, 0, 0);
    f32x4 p2 = __builtin_amdgcn_mfma_f32_16x16x32_bf16(on.v, ar.v, z, 0, 0, 0);
#pragma unroll
    for (int b = 0; b < 4; ++b) {
      irow[b] = ((int)p1[b]) >> 5;
      jcol[b] = ((int)p2[b]) >> 5;
    }
  }

  f32x4 acc[4];
#pragma unroll
  for (int cb = 0; cb < 4; ++cb) acc[cb] = (f32x4){0.f, 0.f, 0.f, 0.f};

  // B staging: image = [kh(8KB)][plane(4KB)][cb(1KB)]; thread slice q of 4:
  //   dst byte q*4096 + tid*16; src = (q&1 ? wpm : wph) + ((q>>1)*16+i)*4096 + tid*16
  const char* wpb0 = (const char*)wph;
  const char* wpb1 = (const char*)wpm;
  uint4 sreg[4];

#define LOADS(i)                                                                     \
  {                                                                                  \
    _Pragma("unroll")                                                                \
    for (int q = 0; q < 4; ++q) {                                                    \
      const char* src = (q & 1) ? wpb1 : wpb0;                                       \
      sreg[q] = *(const uint4*)(src + (((size_t)(q >> 1) * 16 + (i)) << 12) +        \
                                tid * 16);                                           \
    }                                                                                \
  }

#define WRITES(bi)                                                                   \
  {                                                                                  \
    _Pragma("unroll")                                                                \
    for (int q = 0; q < 4; ++q)                                                      \
      *(uint4*)(&Bs[bi][q * 4096 + tid * 16]) = sreg[q];                             \
  }

  const float* aptr = x + (size_t)(m0 + lrow) * DM + g * 8;
  f32x4 aA[2][2];   // [parity][half-of-8-floats]

#define LOADA(i, pa)                                                                 \
  {                                                                                  \
    const f32x4* ap = (const f32x4*)(aptr + (kh * 16 + (i)) * 32);                   \
    aA[pa][0] = ap[0]; aA[pa][1] = ap[1];                                            \
  }

  LOADS(0);
  WRITES(0);
  LOADS(1);
  LOADA(0, 0);
  LOADA(1, 1);

  union { unsigned short u[8]; short8 v; } ah, am;
#pragma unroll
  for (int i = 0; i < 16; ++i) {
    __syncthreads();                     // Bs[i&1] staged & visible; prefetches done
    // split A(i) to bf16x2 (frees aA[i&1] for the i+2 prefetch)
#pragma unroll
    for (int j = 0; j < 8; ++j) {
      float v0 = (j < 4) ? aA[i & 1][0][j] : aA[i & 1][1][j - 4];
      unsigned short h_ = f2bf(v0);
      ah.u[j] = h_; am.u[j] = f2bf(v0 - bf2f(h_));
    }
    if (i + 1 < 16) WRITES((i & 1) ^ 1);           // stage image i+1 (regs from i-1)
    if (i + 2 < 16) {
      LOADS(i + 2);                                // async: lands by barrier i+1
      LOADA(i + 2, i & 1);
    }
    // MFMA from shared B
    {
      const unsigned char* bb = &Bs[i & 1][kh * 8192];
#pragma unroll
      for (int cb = 0; cb < 4; ++cb) {
        short8 bh_ = *(const short8*)(bb + cb * 1024 + lane * 16);
        short8 bm_ = *(const short8*)(bb + 4096 + cb * 1024 + lane * 16);
        acc[cb] = __builtin_amdgcn_mfma_f32_16x16x32_bf16(ah.v, bh_, acc[cb], 0, 0, 0);
        acc[cb] = __builtin_amdgcn_mfma_f32_16x16x32_bf16(am.v, bh_, acc[cb], 0, 0, 0);
        acc[cb] = __builtin_amdgcn_mfma_f32_16x16x32_bf16(ah.v, bm_, acc[cb], 0, 0, 0);
      }
    }
  }

#undef LOADS
#undef WRITES
#undef LOADA

  // --- per-wave partial logits (probe-measured mapping) ---
#pragma unroll
  for (int cb = 0; cb < 4; ++cb)
#pragma unroll
    for (int b = 0; b < 4; ++b)
      Lt[w][irow[b]][cb * 16 + jcol[b]] = acc[cb][b];
  __syncthreads();

  // --- fp32 softmax: 8 threads per token (32 tokens), 8 experts each ---
  {
    float st = temp[0];
    if (st < 0.1f) st = 0.1f;
    const float inv_t = 1.0f / st;
    const int tb = tid >> 3, q8 = tid & 7;
    const int tgt = tb >> 4, t16 = tb & 15;
    float l[8];
    float mx = -1.0e30f;
#pragma unroll
    for (int j = 0; j < 8; ++j) {
      const int e = q8 * 8 + j;
      l[j] = (Lt[tgt * 2][t16][e] + Lt[tgt * 2 + 1][t16][e] + bias[e]) * inv_t;
      mx = fmaxf(mx, l[j]);
    }
    mx = fmaxf(mx, __shfl_xor(mx, 1));
    mx = fmaxf(mx, __shfl_xor(mx, 2));
    mx = fmaxf(mx, __shfl_xor(mx, 4));
    float p[8], s = 0.0f;
#pragma unroll
    for (int j = 0; j < 8; ++j) { p[j] = __expf(l[j] - mx); s += p[j]; }
    s += __shfl_xor(s, 1);
    s += __shfl_xor(s, 2);
    s += __shfl_xor(s, 4);
    const float invs = 1.0f / s;
#pragma unroll
    for (int j = 0; j < 8; ++j) Pt[q8 * 8 + j][tb] = p[j] * invs;
  }
  __syncthreads();

  // --- expert-major store: 4 threads per expert, 32 tokens contiguous ---
  {
    const int e = tid >> 2, qq = tid & 3;
    float* dst = probsT + (size_t)e * GS + blockIdx.x * 32 + qq * 8;
    *(float4*)dst = *(const float4*)(&Pt[e][qq * 8]);
    *(float4*)(dst + 4) = *(const float4*)(&Pt[e][qq * 8 + 4]);
  }
}

// ------------- cooperative bucket pick from a 256-bin histogram (block-wide) ------
__device__ __forceinline__ void pick_scan(const unsigned* __restrict__ bins,
                                          unsigned r_in, unsigned& bucket,
                                          unsigned& r_out, unsigned* res) {
  __syncthreads();
  const int tid = threadIdx.x;
  if (tid < 64) {
    uint4 b = ((const uint4*)bins)[tid];
    unsigned s3 = b.w, s2 = b.z + s3, s1 = b.y + s2, s0 = b.x + s1;
    unsigned suf = s0;
#pragma unroll
    for (int off = 1; off < 64; off <<= 1) {
      unsigned t = __shfl_down(suf, off);
      if (tid + off < 64) suf += t;
    }
    unsigned above = suf - s0;
    unsigned inc0 = above + s0, inc1 = above + s1, inc2 = above + s2, inc3 = above + s3;
    if (inc3 >= r_in && inc3 - b.w < r_in) { res[0] = 4 * tid + 3; res[1] = r_in - (inc3 - b.w); }
    if (inc2 >= r_in && inc2 - b.z < r_in) { res[0] = 4 * tid + 2; res[1] = r_in - (inc2 - b.z); }
    if (inc1 >= r_in && inc1 - b.y < r_in) { res[0] = 4 * tid + 1; res[1] = r_in - (inc1 - b.y); }
    if (inc0 >= r_in && inc0 - b.x < r_in) { res[0] = 4 * tid + 0; res[1] = r_in - (inc0 - b.x); }
  }
  __syncthreads();
  bucket = res[0];
  r_out = res[1];
}

// ---------------- Kernel 2: pass-0 (top-byte) histogram, full scan ----------------
__global__ __launch_bounds__(256)
void k_hist0(const float* __restrict__ probsT, unsigned* __restrict__ ghist0) {
  __shared__ unsigned h[4][256];
  const int tid = threadIdx.x, wv = tid >> 6;
  const int e = blockIdx.x >> 4;
  const int seg = blockIdx.x & (SEG - 1);
  h[0][tid] = 0; h[1][tid] = 0; h[2][tid] = 0; h[3][tid] = 0;
  __syncthreads();
  const float4* col = (const float4*)(probsT + (size_t)e * GS + seg * SEGLEN);
#pragma unroll
  for (int i = 0; i < SEGLEN / 1024; ++i) {
    float4 v = col[i * 256 + tid];
    atomicAdd(&h[wv][__float_as_uint(v.x) >> 24], 1u);
    atomicAdd(&h[wv][__float_as_uint(v.y) >> 24], 1u);
    atomicAdd(&h[wv][__float_as_uint(v.z) >> 24], 1u);
    atomicAdd(&h[wv][__float_as_uint(v.w) >> 24], 1u);
  }
  __syncthreads();
  unsigned c = h[0][tid] + h[1][tid] + h[2][tid] + h[3][tid];
  if (c) atomicAdd(&ghist0[e * 256 + tid], c);
}

// ---------------- Kernel 3: compact tokens with top-byte >= b0-1 ------------------
__global__ __launch_bounds__(256)
void k_compact(const float* __restrict__ probsT, const unsigned* __restrict__ ghist0,
               unsigned* __restrict__ cCnt, int* __restrict__ cIdx,
               float* __restrict__ cKey) {
  __shared__ unsigned res[2];
  __shared__ unsigned locN, basePos;
  __shared__ int locIdx[2048];
  __shared__ float locKey[2048];
  const int tid = threadIdx.x;
  const int e = blockIdx.x >> 4;
  const int seg = blockIdx.x & (SEG - 1);

  if (tid == 0) locN = 0u;
  unsigned b0, r0;
  pick_scan(ghist0 + e * 256, KSEL, b0, r0, res);
  const unsigned blo = (b0 == 0u) ? 0u : (b0 - 1u);

  const float* col = probsT + (size_t)e * GS + seg * SEGLEN;
  for (int i = 0; i < SEGLEN / 256; ++i) {
    const int t = i * 256 + tid;
    const float p = col[t];
    if ((__float_as_uint(p) >> 24) >= blo) {
      unsigned pos = atomicAdd(&locN, 1u);
      locIdx[pos] = seg * SEGLEN + t;
      locKey[pos] = p;
    }
  }
  __syncthreads();
  if (tid == 0) basePos = locN ? atomicAdd(&cCnt[e], locN) : 0u;
  __syncthreads();
  const unsigned n = locN, bp = basePos;
  for (unsigned i = tid; i < n; i += 256) {
    const unsigned gp = bp + i;
    if (gp < CAP2) {
      cIdx[(size_t)e * CAP2 + gp] = locIdx[i];
      cKey[(size_t)e * CAP2 + gp] = locKey[i];
    }
  }
}

// ---------------- Kernel 4: per-expert radix passes 1-3 + classify ----------------
__global__ __launch_bounds__(256)
void k_select2(const unsigned* __restrict__ ghist0, const unsigned* __restrict__ cCnt,
               const int* __restrict__ cIdx, const float* __restrict__ cKey,
               const float* __restrict__ temp, unsigned* __restrict__ defCnt,
               unsigned* __restrict__ candCnt, int* __restrict__ candIdx,
               float* __restrict__ thrHiA) {
  __shared__ unsigned res[2];
  __shared__ unsigned h[4][256];
  __shared__ unsigned hs[256];
  __shared__ unsigned nd, nc;
  const int tid = threadIdx.x, wv = tid >> 6;
  const int e = blockIdx.x;
  const int cnt = (int)min(cCnt[e], (unsigned)CAP2);

  unsigned b0, r;
  pick_scan(ghist0 + e * 256, KSEL, b0, r, res);
  unsigned pfx = b0 << 24;

  for (int pass = 1; pass < 4; ++pass) {
    const int shift = 24 - 8 * pass;
    const unsigned hm = 0xFFFFFFFFu << (shift + 8);
    for (int i = tid; i < 1024; i += 256) ((unsigned*)h)[i] = 0u;
    __syncthreads();
    for (int i = tid; i < cnt; i += 256) {
      unsigned key = __float_as_uint(cKey[(size_t)e * CAP2 + i]);
      if ((key & hm) == (pfx & hm)) atomicAdd(&h[wv][(key >> shift) & 255], 1u);
    }
    __syncthreads();
    hs[tid] = h[0][tid] + h[1][tid] + h[2][tid] + h[3][tid];
    unsigned b, rn;
    pick_scan(hs, r, b, rn, res);
    pfx |= b << shift;
    r = rn;
  }

  const float thrv = __uint_as_float(pfx);
  float st = temp[0];
  if (st < 0.1f) st = 0.1f;
  const float rel = 2.0e-3f / st;
  const float hi = thrv * (1.0f + rel);
  const float lo = thrv * (1.0f - rel);
  if (tid == 0) thrHiA[e] = hi;

  if (tid == 0) { nd = 0u; nc = 0u; }
  __syncthreads();
  for (int i = tid; i < cnt; i += 256) {
    const float p = cKey[(size_t)e * CAP2 + i];
    const int t = cIdx[(size_t)e * CAP2 + i];
    if (p > hi) {
      atomicAdd(&nd, 1u);
    } else if (p >= lo) {
      unsigned pos = atomicAdd(&nc, 1u);
      if (pos < CAP) candIdx[e * CAP + pos] = t;
    }
  }
  __syncthreads();
  if (tid == 0) {
    defCnt[e] = nd;
    candCnt[e] = min(nc, (unsigned)CAP);
  }
}

// ---------------- Kernel 5: exact fp64 recompute of candidate probabilities -------
__global__ __launch_bounds__(256)
void k_repair(const float* __restrict__ x, const float* __restrict__ w,
              const float* __restrict__ bias, const float* __restrict__ temp,
              const unsigned* __restrict__ candCnt, const int* __restrict__ candIdx,
              double* __restrict__ candKey) {
  __shared__ double red[4][64];
  const int e = blockIdx.x >> 4;
  const int chunk = blockIdx.x & 15;
  const int tid = threadIdx.x;
  const int ee = tid & 63, q = tid >> 6;
  const int cnt = (int)min(candCnt[e], (unsigned)CAP);

  double st = (double)temp[0];
  if (st < 0.1) st = 0.1;
  const double inv_t = 1.0 / st;

  for (int i = chunk; i < cnt; i += 16) {
    const int t = candIdx[e * CAP + i];
    const float* xr = x + (size_t)t * DM;
    double s0 = 0.0, s1 = 0.0, s2 = 0.0, s3 = 0.0;
    const int kb = q * 256;
    for (int k = kb; k < kb + 256; k += 4) {
      s0 += (double)xr[k + 0] * (double)w[(size_t)(k + 0) * NE + ee];
      s1 += (double)xr[k + 1] * (double)w[(size_t)(k + 1) * NE + ee];
      s2 += (double)xr[k + 2] * (double)w[(size_t)(k + 2) * NE + ee];
      s3 += (double)xr[k + 3] * (double)w[(size_t)(k + 3) * NE + ee];
    }
    red[q][ee] = (s0 + s1) + (s2 + s3);
    __syncthreads();
    if (tid < 64) {
      double l = (red[0][tid] + red[1][tid] + red[2][tid] + red[3][tid] +
                  (double)bias[tid]) * inv_t;
      double m = l;
#pragma unroll
      for (int off = 1; off < 64; off <<= 1) m = fmax(m, __shfl_xor(m, off));
      double ex = exp(l - m);
      double ss = ex;
#pragma unroll
      for (int off = 1; off < 64; off <<= 1) ss += __shfl_xor(ss, off);
      if (tid == e) candKey[e * CAP + i] = ex / ss;
    }
    __syncthreads();
  }
}

// ---------------- Kernel 6: dense mask scatter (definite region) + loss -----------
__global__ __launch_bounds__(256)
void k_scatter(const float* __restrict__ probsT, const float* __restrict__ thrHiA,
               float* __restrict__ out) {
  const int gid = blockIdx.x * 256 + threadIdx.x;
  const int base = gid * 4;
  const int e = base >> 15;
  float4 p = *(const float4*)(probsT + (size_t)base);
  const float hi = thrHiA[e];
  float pv[4] = {p.x, p.y, p.z, p.w};
  float mk[4], wt[4];
#pragma unroll
  for (int c = 0; c < 4; ++c) {
    bool sel = pv[c] > hi;
    mk[c] = sel ? 1.0f : 0.0f;
    wt[c] = sel ? pv[c] : 0.0f;
  }
  *(float4*)(out + (size_t)base) = make_float4(mk[0], mk[1], mk[2], mk[3]);
  *(float4*)(out + (size_t)MASK_ELEMS + base) = make_float4(wt[0], wt[1], wt[2], wt[3]);
  if (gid == 0) out[2 * (size_t)MASK_ELEMS] = 0.0f;
}

// ---------------- Kernel 7: rank candidates, patch selected into output -----------
__global__ __launch_bounds__(256)
void k_finish(const unsigned* __restrict__ defCnt, const unsigned* __restrict__ candCnt,
              const int* __restrict__ candIdx, const double* __restrict__ candKey,
              const float* __restrict__ probsT, float* __restrict__ out) {
  __shared__ double kd[CAP];
  __shared__ int ti[CAP];
  const int e = blockIdx.x, tid = threadIdx.x;
  const int cnt = (int)min(candCnt[e], (unsigned)CAP);
  const int need = KSEL - (int)defCnt[e];

  for (int i = tid; i < cnt; i += 256) {
    kd[i] = candKey[e * CAP + i];
    ti[i] = candIdx[e * CAP + i];
  }
  __syncthreads();
  for (int i = tid; i < cnt; i += 256) {
    const double ki = kd[i];
    const int tii = ti[i];
    int rank = 0;
    for (int j = 0; j < cnt; ++j)
      rank += (kd[j] > ki) || (kd[j] == ki && ti[j] < tii);
    if (rank < need) {
      out[(size_t)e * GS + tii] = 1.0f;
      out[(size_t)MASK_ELEMS + (size_t)e * GS + tii] = probsT[(size_t)e * GS + tii];
    }
  }
}

extern "C" void kernel_launch(void* const* d_in, const int* in_sizes, int n_in,
                              void* d_out, int out_size, void* d_ws, size_t ws_size,
                              hipStream_t stream) {
  const float* x    = (const float*)d_in[0];
  const float* gw   = (const float*)d_in[1];
  const float* gb   = (const float*)d_in[2];
  const float* temp = (const float*)d_in[3];

  float* probsT    = (float*)d_ws;                                        // 8MB
  unsigned* ghist0 = (unsigned*)((char*)d_ws + (size_t)MASK_ELEMS * 4);   // 64KB
  unsigned* cCnt   = ghist0 + NE * 256;                                   // 256B
  unsigned* defCnt = cCnt + NE;                                           // 256B
  unsigned* candCnt = defCnt + NE;                                        // 256B
  float* thrHiA    = (float*)(candCnt + NE);                              // 256B
  int* candIdx     = (int*)(thrHiA + NE);                                 // 512KB
  double* candKey  = (double*)(candIdx + NE * CAP);                       // 1MB
  int* cIdx        = (int*)(candKey + NE * CAP);                          // 4MB
  float* cKey      = (float*)(cIdx + (size_t)NE * CAP2);                  // 4MB
  unsigned short* wph = (unsigned short*)(cKey + (size_t)NE * CAP2);      // 128KB
  unsigned short* wpm = wph + DM * NE;                                    // 128KB

  k_split<<<DM * NE / 256, 256, 0, stream>>>(gw, wph, wpm, ghist0);
  k_gemm_softmax<<<GS / 32, 256, 0, stream>>>(x, wph, wpm, gb, temp, probsT);
  k_hist0<<<NE * SEG, 256, 0, stream>>>(probsT, ghist0);
  k_compact<<<NE * SEG, 256, 0, stream>>>(probsT, ghist0, cCnt, cIdx, cKey);
  k_select2<<<NE, 256, 0, stream>>>(ghist0, cCnt, cIdx, cKey, temp, defCnt,
                                    candCnt, candIdx, thrHiA);
  k_repair<<<NE * 16, 256, 0, stream>>>(x, gw, gb, temp, candCnt, candIdx, candKey);
  k_scatter<<<MASK_ELEMS / 1024, 256, 0, stream>>>(probsT, thrHiA, (float*)d_out);
  k_finish<<<NE, 256, 0, stream>>>(defCnt, candCnt, candIdx, candKey,
                                   probsT, (float*)d_out);
}

// Round 20
// 95.203 us; speedup vs baseline: 1.5359x; 1.5359x over previous
//
#include <hip/hip_runtime.h>
#include <math.h>

#define NG 8
#define SEQ 4096
#define DM 1024
#define NE 64
#define GS (NG * SEQ)          // 32768 tokens
#define KSEL 1024              // expert capacity
#define MASK_ELEMS (NE * GS)   // 2097152
#define SEG 16
#define SEGLEN (GS / SEG)
#define CAP 2048               // max repair candidates per expert
#define CAP2 16384             // max compacted entries per expert

typedef __attribute__((ext_vector_type(8))) short short8;
typedef __attribute__((ext_vector_type(4))) float f32x4;

__device__ __forceinline__ unsigned short f2bf(float v) {   // RN-even
  unsigned u = __float_as_uint(v);
  return (unsigned short)((u + 0x7FFFu + ((u >> 16) & 1u)) >> 16);
}
__device__ __forceinline__ float bf2f(unsigned short h) {
  return __uint_as_float(((unsigned)h) << 16);
}

// ---------------- Kernel 0: weight split (wave-fragment order) + counter zeroing --
__global__ __launch_bounds__(256)
void k_split(const float* __restrict__ w, unsigned short* __restrict__ wph,
             unsigned short* __restrict__ wpm, unsigned* __restrict__ zbase) {
  const int t = blockIdx.x * 256 + threadIdx.x;
  if (t < NE * 256 + NE) zbase[t] = 0u;
  const int k = t >> 6, e = t & 63;
  float v = w[t];
  unsigned short h = f2bf(v); float r = v - bf2f(h);
  const int tile = k >> 5, g = (k >> 3) & 3, j = k & 7;
  const int cb = e >> 4, lrow = e & 15;
  const size_t o = (size_t)(tile * 4 + cb) * 512 + (g * 16 + lrow) * 8 + j;
  wph[o] = h; wpm[o] = f2bf(r);
}

// ---------------- Kernel 1: bf16x2 MFMA GEMM, 64 tokens/wave (high intensity) -----
// Rounds 14-18: all schedules converge at ~80us with ~10 loads per 16-token tile;
// L3-resident replays identical -> load-issue/latency bound, not BW. Fix: 64
// tokens/wave (4 row-frags share each B fragment): 4 loads/token (2.5x fewer),
// B traffic 512->128MB, 48 MFMA/tile. Block = 4 waves K-split; grid 512 = 2/CU.
__global__ __launch_bounds__(256, 2)
void k_gemm_softmax(const float* __restrict__ x,
                    const unsigned short* __restrict__ wph,
                    const unsigned short* __restrict__ wpm,
                    const float* __restrict__ bias, const float* __restrict__ temp,
                    float* __restrict__ probsT) {
  __shared__ float Lt[4][64][68];                 // 69.6 KB
  float (*Pt)[68] = (float (*)[68])&Lt[0][0][0];  // overlay after reduction

  const int tid = threadIdx.x;
  const int w = tid >> 6, lane = tid & 63;
  const int lrow = lane & 15, g = lane >> 4;
  const int m0 = blockIdx.x * 64;

  // --- probes: C/D (lane,reg)->(i,j) for mfma_f32_16x16x32_bf16 (exact ints) ---
  int irow[4], jcol[4];
  {
    union { unsigned short u[8]; short8 v; } ar, on;
#pragma unroll
    for (int j = 0; j < 8; ++j) { ar.u[j] = f2bf((float)lrow); on.u[j] = 0x3F80u; }
    f32x4 z = {0.f, 0.f, 0.f, 0.f};
    f32x4 p1 = __builtin_amdgcn_mfma_f32_16x16x32_bf16(ar.v, on.v, z, 0, 0, 0);
    f32x4 p2 = __builtin_amdgcn_mfma_f32_16x16x32_bf16(on.v, ar.v, z, 0, 0, 0);
#pragma unroll
    for (int b = 0; b < 4; ++b) {
      irow[b] = ((int)p1[b]) >> 5;
      jcol[b] = ((int)p2[b]) >> 5;
    }
  }

  f32x4 acc[4][4];   // [row-frag][col-block]
#pragma unroll
  for (int rf = 0; rf < 4; ++rf)
#pragma unroll
    for (int cb = 0; cb < 4; ++cb) acc[rf][cb] = (f32x4){0.f, 0.f, 0.f, 0.f};

  const int boff = lane * 8;
  const int T0 = w * 8;             // wave's k-tiles: T0..T0+7 (K = w*256..+255)

  f32x4 aP[4][2], aQ[4][2];         // A f32 ping-pong, per row-frag
  short8 bhP[4], bmP[4], bhQ[4], bmQ[4];

#define LOADA_(T, ar)                                                                \
  {                                                                                  \
    _Pragma("unroll")                                                                \
    for (int rf = 0; rf < 4; ++rf) {                                                 \
      const f32x4* ap = (const f32x4*)(x + (size_t)(m0 + rf * 16 + lrow) * DM +      \
                                       (T) * 32 + g * 8);                            \
      ar[rf][0] = ap[0]; ar[rf][1] = ap[1];                                          \
    }                                                                                \
  }

#define LOADB_(T, bh, bm)                                                            \
  {                                                                                  \
    _Pragma("unroll")                                                                \
    for (int cb = 0; cb < 4; ++cb) {                                                 \
      const size_t bo = (size_t)((T) * 4 + cb) * 512 + boff;                         \
      bh[cb] = *(const short8*)(wph + bo);                                           \
      bm[cb] = *(const short8*)(wpm + bo);                                           \
    }                                                                                \
  }

#define SPLIT_MFMA(ar, bh, bm)                                                       \
  {                                                                                  \
    _Pragma("unroll")                                                                \
    for (int rf = 0; rf < 4; ++rf) {                                                 \
      union { unsigned short u[8]; short8 v; } ah, am;                               \
      _Pragma("unroll")                                                              \
      for (int j = 0; j < 8; ++j) {                                                  \
        float v0 = (j < 4) ? ar[rf][0][j] : ar[rf][1][j - 4];                        \
        unsigned short h_ = f2bf(v0);                                                \
        ah.u[j] = h_; am.u[j] = f2bf(v0 - bf2f(h_));                                 \
      }                                                                              \
      _Pragma("unroll")                                                              \
      for (int cb = 0; cb < 4; ++cb) {                                               \
        acc[rf][cb] = __builtin_amdgcn_mfma_f32_16x16x32_bf16(ah.v, bh[cb],          \
                                                              acc[rf][cb], 0, 0, 0); \
        acc[rf][cb] = __builtin_amdgcn_mfma_f32_16x16x32_bf16(am.v, bh[cb],          \
                                                              acc[rf][cb], 0, 0, 0); \
        acc[rf][cb] = __builtin_amdgcn_mfma_f32_16x16x32_bf16(ah.v, bm[cb],          \
                                                              acc[rf][cb], 0, 0, 0); \
      }                                                                              \
    }                                                                                \
  }

  LOADA_(T0, aP);
  LOADB_(T0, bhP, bmP);
#pragma unroll
  for (int t = 0; t < 8; t += 2) {
    LOADA_(T0 + t + 1, aQ);            // issue next-tile loads before compute
    LOADB_(T0 + t + 1, bhQ, bmQ);
    SPLIT_MFMA(aP, bhP, bmP);          // tile t
    if (t + 2 < 8) {
      LOADA_(T0 + t + 2, aP);
      LOADB_(T0 + t + 2, bhP, bmP);
    }
    SPLIT_MFMA(aQ, bhQ, bmQ);          // tile t+1
  }

#undef LOADA_
#undef LOADB_
#undef SPLIT_MFMA

  // --- per-wave partial logits (probe-measured mapping) ---
#pragma unroll
  for (int rf = 0; rf < 4; ++rf)
#pragma unroll
    for (int cb = 0; cb < 4; ++cb)
#pragma unroll
      for (int b = 0; b < 4; ++b)
        Lt[w][rf * 16 + irow[b]][cb * 16 + jcol[b]] = acc[rf][cb][b];
  __syncthreads();

  // --- fp32 softmax: 4 threads per token (64 tokens), 16 experts each ---
  float pr[16];
  const int tk = tid >> 2, q = tid & 3;
  {
    float st = temp[0];
    if (st < 0.1f) st = 0.1f;
    const float inv_t = 1.0f / st;
    float l[16];
    float mx = -1.0e30f;
#pragma unroll
    for (int j = 0; j < 16; ++j) {
      const int e = q * 16 + j;
      l[j] = (Lt[0][tk][e] + Lt[1][tk][e] + Lt[2][tk][e] + Lt[3][tk][e] + bias[e]) *
             inv_t;
      mx = fmaxf(mx, l[j]);
    }
    mx = fmaxf(mx, __shfl_xor(mx, 1));
    mx = fmaxf(mx, __shfl_xor(mx, 2));
    float p[16], s = 0.0f;
#pragma unroll
    for (int j = 0; j < 16; ++j) { p[j] = __expf(l[j] - mx); s += p[j]; }
    s += __shfl_xor(s, 1);
    s += __shfl_xor(s, 2);
    const float invs = 1.0f / s;
#pragma unroll
    for (int j = 0; j < 16; ++j) pr[j] = p[j] * invs;
  }
  __syncthreads();   // all Lt reads complete before Pt overlay
#pragma unroll
  for (int j = 0; j < 16; ++j) Pt[q * 16 + j][tk] = pr[j];
  __syncthreads();

  // --- expert-major store: 4 threads per expert, 64 tokens contiguous (256B) ---
  {
    const int e = tid >> 2, qq = tid & 3;
    float* dst = probsT + (size_t)e * GS + m0 + qq * 16;
#pragma unroll
    for (int c2 = 0; c2 < 4; ++c2)
      *(float4*)(dst + c2 * 4) = *(const float4*)(&Pt[e][qq * 16 + c2 * 4]);
  }
}

// ------------- cooperative bucket pick from a 256-bin histogram (block-wide) ------
__device__ __forceinline__ void pick_scan(const unsigned* __restrict__ bins,
                                          unsigned r_in, unsigned& bucket,
                                          unsigned& r_out, unsigned* res) {
  __syncthreads();
  const int tid = threadIdx.x;
  if (tid < 64) {
    uint4 b = ((const uint4*)bins)[tid];
    unsigned s3 = b.w, s2 = b.z + s3, s1 = b.y + s2, s0 = b.x + s1;
    unsigned suf = s0;
#pragma unroll
    for (int off = 1; off < 64; off <<= 1) {
      unsigned t = __shfl_down(suf, off);
      if (tid + off < 64) suf += t;
    }
    unsigned above = suf - s0;
    unsigned inc0 = above + s0, inc1 = above + s1, inc2 = above + s2, inc3 = above + s3;
    if (inc3 >= r_in && inc3 - b.w < r_in) { res[0] = 4 * tid + 3; res[1] = r_in - (inc3 - b.w); }
    if (inc2 >= r_in && inc2 - b.z < r_in) { res[0] = 4 * tid + 2; res[1] = r_in - (inc2 - b.z); }
    if (inc1 >= r_in && inc1 - b.y < r_in) { res[0] = 4 * tid + 1; res[1] = r_in - (inc1 - b.y); }
    if (inc0 >= r_in && inc0 - b.x < r_in) { res[0] = 4 * tid + 0; res[1] = r_in - (inc0 - b.x); }
  }
  __syncthreads();
  bucket = res[0];
  r_out = res[1];
}

// ---------------- Kernel 2: pass-0 (top-byte) histogram, full scan ----------------
__global__ __launch_bounds__(256)
void k_hist0(const float* __restrict__ probsT, unsigned* __restrict__ ghist0) {
  __shared__ unsigned h[4][256];
  const int tid = threadIdx.x, wv = tid >> 6;
  const int e = blockIdx.x >> 4;
  const int seg = blockIdx.x & (SEG - 1);
  h[0][tid] = 0; h[1][tid] = 0; h[2][tid] = 0; h[3][tid] = 0;
  __syncthreads();
  const float4* col = (const float4*)(probsT + (size_t)e * GS + seg * SEGLEN);
#pragma unroll
  for (int i = 0; i < SEGLEN / 1024; ++i) {
    float4 v = col[i * 256 + tid];
    atomicAdd(&h[wv][__float_as_uint(v.x) >> 24], 1u);
    atomicAdd(&h[wv][__float_as_uint(v.y) >> 24], 1u);
    atomicAdd(&h[wv][__float_as_uint(v.z) >> 24], 1u);
    atomicAdd(&h[wv][__float_as_uint(v.w) >> 24], 1u);
  }
  __syncthreads();
  unsigned c = h[0][tid] + h[1][tid] + h[2][tid] + h[3][tid];
  if (c) atomicAdd(&ghist0[e * 256 + tid], c);
}

// ---------------- Kernel 3: compact tokens with top-byte >= b0-1 ------------------
__global__ __launch_bounds__(256)
void k_compact(const float* __restrict__ probsT, const unsigned* __restrict__ ghist0,
               unsigned* __restrict__ cCnt, int* __restrict__ cIdx,
               float* __restrict__ cKey) {
  __shared__ unsigned res[2];
  __shared__ unsigned locN, basePos;
  __shared__ int locIdx[2048];
  __shared__ float locKey[2048];
  const int tid = threadIdx.x;
  const int e = blockIdx.x >> 4;
  const int seg = blockIdx.x & (SEG - 1);

  if (tid == 0) locN = 0u;
  unsigned b0, r0;
  pick_scan(ghist0 + e * 256, KSEL, b0, r0, res);
  const unsigned blo = (b0 == 0u) ? 0u : (b0 - 1u);

  const float* col = probsT + (size_t)e * GS + seg * SEGLEN;
  for (int i = 0; i < SEGLEN / 256; ++i) {
    const int t = i * 256 + tid;
    const float p = col[t];
    if ((__float_as_uint(p) >> 24) >= blo) {
      unsigned pos = atomicAdd(&locN, 1u);
      locIdx[pos] = seg * SEGLEN + t;
      locKey[pos] = p;
    }
  }
  __syncthreads();
  if (tid == 0) basePos = locN ? atomicAdd(&cCnt[e], locN) : 0u;
  __syncthreads();
  const unsigned n = locN, bp = basePos;
  for (unsigned i = tid; i < n; i += 256) {
    const unsigned gp = bp + i;
    if (gp < CAP2) {
      cIdx[(size_t)e * CAP2 + gp] = locIdx[i];
      cKey[(size_t)e * CAP2 + gp] = locKey[i];
    }
  }
}

// ---------------- Kernel 4: per-expert radix passes 1-3 + classify ----------------
__global__ __launch_bounds__(256)
void k_select2(const unsigned* __restrict__ ghist0, const unsigned* __restrict__ cCnt,
               const int* __restrict__ cIdx, const float* __restrict__ cKey,
               const float* __restrict__ temp, unsigned* __restrict__ defCnt,
               unsigned* __restrict__ candCnt, int* __restrict__ candIdx,
               float* __restrict__ thrHiA) {
  __shared__ unsigned res[2];
  __shared__ unsigned h[4][256];
  __shared__ unsigned hs[256];
  __shared__ unsigned nd, nc;
  const int tid = threadIdx.x, wv = tid >> 6;
  const int e = blockIdx.x;
  const int cnt = (int)min(cCnt[e], (unsigned)CAP2);

  unsigned b0, r;
  pick_scan(ghist0 + e * 256, KSEL, b0, r, res);
  unsigned pfx = b0 << 24;

  for (int pass = 1; pass < 4; ++pass) {
    const int shift = 24 - 8 * pass;
    const unsigned hm = 0xFFFFFFFFu << (shift + 8);
    for (int i = tid; i < 1024; i += 256) ((unsigned*)h)[i] = 0u;
    __syncthreads();
    for (int i = tid; i < cnt; i += 256) {
      unsigned key = __float_as_uint(cKey[(size_t)e * CAP2 + i]);
      if ((key & hm) == (pfx & hm)) atomicAdd(&h[wv][(key >> shift) & 255], 1u);
    }
    __syncthreads();
    hs[tid] = h[0][tid] + h[1][tid] + h[2][tid] + h[3][tid];
    unsigned b, rn;
    pick_scan(hs, r, b, rn, res);
    pfx |= b << shift;
    r = rn;
  }

  const float thrv = __uint_as_float(pfx);
  float st = temp[0];
  if (st < 0.1f) st = 0.1f;
  const float rel = 2.0e-3f / st;
  const float hi = thrv * (1.0f + rel);
  const float lo = thrv * (1.0f - rel);
  if (tid == 0) thrHiA[e] = hi;

  if (tid == 0) { nd = 0u; nc = 0u; }
  __syncthreads();
  for (int i = tid; i < cnt; i += 256) {
    const float p = cKey[(size_t)e * CAP2 + i];
    const int t = cIdx[(size_t)e * CAP2 + i];
    if (p > hi) {
      atomicAdd(&nd, 1u);
    } else if (p >= lo) {
      unsigned pos = atomicAdd(&nc, 1u);
      if (pos < CAP) candIdx[e * CAP + pos] = t;
    }
  }
  __syncthreads();
  if (tid == 0) {
    defCnt[e] = nd;
    candCnt[e] = min(nc, (unsigned)CAP);
  }
}

// ---------------- Kernel 5: exact fp64 recompute of candidate probabilities -------
__global__ __launch_bounds__(256)
void k_repair(const float* __restrict__ x, const float* __restrict__ w,
              const float* __restrict__ bias, const float* __restrict__ temp,
              const unsigned* __restrict__ candCnt, const int* __restrict__ candIdx,
              double* __restrict__ candKey) {
  __shared__ double red[4][64];
  const int e = blockIdx.x >> 4;
  const int chunk = blockIdx.x & 15;
  const int tid = threadIdx.x;
  const int ee = tid & 63, q = tid >> 6;
  const int cnt = (int)min(candCnt[e], (unsigned)CAP);

  double st = (double)temp[0];
  if (st < 0.1) st = 0.1;
  const double inv_t = 1.0 / st;

  for (int i = chunk; i < cnt; i += 16) {
    const int t = candIdx[e * CAP + i];
    const float* xr = x + (size_t)t * DM;
    double s0 = 0.0, s1 = 0.0, s2 = 0.0, s3 = 0.0;
    const int kb = q * 256;
    for (int k = kb; k < kb + 256; k += 4) {
      s0 += (double)xr[k + 0] * (double)w[(size_t)(k + 0) * NE + ee];
      s1 += (double)xr[k + 1] * (double)w[(size_t)(k + 1) * NE + ee];
      s2 += (double)xr[k + 2] * (double)w[(size_t)(k + 2) * NE + ee];
      s3 += (double)xr[k + 3] * (double)w[(size_t)(k + 3) * NE + ee];
    }
    red[q][ee] = (s0 + s1) + (s2 + s3);
    __syncthreads();
    if (tid < 64) {
      double l = (red[0][tid] + red[1][tid] + red[2][tid] + red[3][tid] +
                  (double)bias[tid]) * inv_t;
      double m = l;
#pragma unroll
      for (int off = 1; off < 64; off <<= 1) m = fmax(m, __shfl_xor(m, off));
      double ex = exp(l - m);
      double ss = ex;
#pragma unroll
      for (int off = 1; off < 64; off <<= 1) ss += __shfl_xor(ss, off);
      if (tid == e) candKey[e * CAP + i] = ex / ss;
    }
    __syncthreads();
  }
}

// ---------------- Kernel 6: dense mask scatter (definite region) + loss -----------
__global__ __launch_bounds__(256)
void k_scatter(const float* __restrict__ probsT, const float* __restrict__ thrHiA,
               float* __restrict__ out) {
  const int gid = blockIdx.x * 256 + threadIdx.x;
  const int base = gid * 4;
  const int e = base >> 15;
  float4 p = *(const float4*)(probsT + (size_t)base);
  const float hi = thrHiA[e];
  float pv[4] = {p.x, p.y, p.z, p.w};
  float mk[4], wt[4];
#pragma unroll
  for (int c = 0; c < 4; ++c) {
    bool sel = pv[c] > hi;
    mk[c] = sel ? 1.0f : 0.0f;
    wt[c] = sel ? pv[c] : 0.0f;
  }
  *(float4*)(out + (size_t)base) = make_float4(mk[0], mk[1], mk[2], mk[3]);
  *(float4*)(out + (size_t)MASK_ELEMS + base) = make_float4(wt[0], wt[1], wt[2], wt[3]);
  if (gid == 0) out[2 * (size_t)MASK_ELEMS] = 0.0f;
}

// ---------------- Kernel 7: rank candidates, patch selected into output -----------
__global__ __launch_bounds__(256)
void k_finish(const unsigned* __restrict__ defCnt, const unsigned* __restrict__ candCnt,
              const int* __restrict__ candIdx, const double* __restrict__ candKey,
              const float* __restrict__ probsT, float* __restrict__ out) {
  __shared__ double kd[CAP];
  __shared__ int ti[CAP];
  const int e = blockIdx.x, tid = threadIdx.x;
  const int cnt = (int)min(candCnt[e], (unsigned)CAP);
  const int need = KSEL - (int)defCnt[e];

  for (int i = tid; i < cnt; i += 256) {
    kd[i] = candKey[e * CAP + i];
    ti[i] = candIdx[e * CAP + i];
  }
  __syncthreads();
  for (int i = tid; i < cnt; i += 256) {
    const double ki = kd[i];
    const int tii = ti[i];
    int rank = 0;
    for (int j = 0; j < cnt; ++j)
      rank += (kd[j] > ki) || (kd[j] == ki && ti[j] < tii);
    if (rank < need) {
      out[(size_t)e * GS + tii] = 1.0f;
      out[(size_t)MASK_ELEMS + (size_t)e * GS + tii] = probsT[(size_t)e * GS + tii];
    }
  }
}

extern "C" void kernel_launch(void* const* d_in, const int* in_sizes, int n_in,
                              void* d_out, int out_size, void* d_ws, size_t ws_size,
                              hipStream_t stream) {
  const float* x    = (const float*)d_in[0];
  const float* gw   = (const float*)d_in[1];
  const float* gb   = (const float*)d_in[2];
  const float* temp = (const float*)d_in[3];

  float* probsT    = (float*)d_ws;                                        // 8MB
  unsigned* ghist0 = (unsigned*)((char*)d_ws + (size_t)MASK_ELEMS * 4);   // 64KB
  unsigned* cCnt   = ghist0 + NE * 256;                                   // 256B
  unsigned* defCnt = cCnt + NE;                                           // 256B
  unsigned* candCnt = defCnt + NE;                                        // 256B
  float* thrHiA    = (float*)(candCnt + NE);                              // 256B
  int* candIdx     = (int*)(thrHiA + NE);                                 // 512KB
  double* candKey  = (double*)(candIdx + NE * CAP);                       // 1MB
  int* cIdx        = (int*)(candKey + NE * CAP);                          // 4MB
  float* cKey      = (float*)(cIdx + (size_t)NE * CAP2);                  // 4MB
  unsigned short* wph = (unsigned short*)(cKey + (size_t)NE * CAP2);      // 128KB
  unsigned short* wpm = wph + DM * NE;                                    // 128KB

  k_split<<<DM * NE / 256, 256, 0, stream>>>(gw, wph, wpm, ghist0);
  k_gemm_softmax<<<GS / 64, 256, 0, stream>>>(x, wph, wpm, gb, temp, probsT);
  k_hist0<<<NE * SEG, 256, 0, stream>>>(probsT, ghist0);
  k_compact<<<NE * SEG, 256, 0, stream>>>(probsT, ghist0, cCnt, cIdx, cKey);
  k_select2<<<NE, 256, 0, stream>>>(ghist0, cCnt, cIdx, cKey, temp, defCnt,
                                    candCnt, candIdx, thrHiA);
  k_repair<<<NE * 16, 256, 0, stream>>>(x, gw, gb, temp, candCnt, candIdx, candKey);
  k_scatter<<<MASK_ELEMS / 1024, 256, 0, stream>>>(probsT, thrHiA, (float*)d_out);
  k_finish<<<NE, 256, 0, stream>>>(defCnt, candCnt, candIdx, candKey,
                                   probsT, (float*)d_out);
}

// Round 21
// 94.939 us; speedup vs baseline: 1.5402x; 1.0028x over previous
//
#include <hip/hip_runtime.h>
#include <math.h>

#define NG 8
#define SEQ 4096
#define DM 1024
#define NE 64
#define GS (NG * SEQ)          // 32768 tokens
#define KSEL 1024              // expert capacity
#define MASK_ELEMS (NE * GS)   // 2097152
#define SEG 16
#define SEGLEN (GS / SEG)
#define CAP 2048               // max repair candidates per expert
#define CAP2 16384             // max compacted entries per expert

typedef __attribute__((ext_vector_type(8))) short short8;
typedef __attribute__((ext_vector_type(4))) float f32x4;

__device__ __forceinline__ unsigned short f2bf(float v) {   // RN-even
  unsigned u = __float_as_uint(v);
  return (unsigned short)((u + 0x7FFFu + ((u >> 16) & 1u)) >> 16);
}
__device__ __forceinline__ float bf2f(unsigned short h) {
  return __uint_as_float(((unsigned)h) << 16);
}

// ---------------- Kernel 0: weight split (wave-fragment order) + counter zeroing --
__global__ __launch_bounds__(256)
void k_split(const float* __restrict__ w, unsigned short* __restrict__ wph,
             unsigned short* __restrict__ wpm, unsigned* __restrict__ zbase) {
  const int t = blockIdx.x * 256 + threadIdx.x;
  if (t < NE * 256 + NE) zbase[t] = 0u;
  const int k = t >> 6, e = t & 63;
  float v = w[t];
  unsigned short h = f2bf(v); float r = v - bf2f(h);
  const int tile = k >> 5, g = (k >> 3) & 3, j = k & 7;
  const int cb = e >> 4, lrow = e & 15;
  const size_t o = (size_t)(tile * 4 + cb) * 512 + (g * 16 + lrow) * 8 + j;
  wph[o] = h; wpm[o] = f2bf(r);
}

// ---------------- Kernel 1: bf16x2 MFMA GEMM — coalesced A via wave-private LDS ---
// Round-20 diagnosis: A-frag loads (lane row-stride 4KB) touch 64 cache lines per
// instruction -> ~8.4M line-requests; the per-CU request queue serializes them at
// ~L3 latency = the schedule-invariant ~70-85us wall of rounds 14-20. Fix: stage A
// through wave-private LDS with COALESCED loads (8 lines/instr), stride-36 rows
// (2-way frag reads = free), no barriers (producer==consumer wave); keep r20's
// B register ping-pong (fragment-ordered, coalesced) and full VGPR budget.
__global__ __launch_bounds__(256, 2)
void k_gemm_softmax(const float* __restrict__ x,
                    const unsigned short* __restrict__ wph,
                    const unsigned short* __restrict__ wpm,
                    const float* __restrict__ bias, const float* __restrict__ temp,
                    float* __restrict__ probsT) {
  __shared__ float S[18432];                      // 72 KB
  // per-wave A staging: S[w*4608 + buf*2304 + row*36 + col], row<64, col<32
  float (*Lt)[64][68] = (float (*)[64][68])S;     // overlay after K-loop (69.6 KB)
  float (*Pt)[68] = (float (*)[68])S;             // overlay after reduction

  const int tid = threadIdx.x;
  const int w = tid >> 6, lane = tid & 63;
  const int lrow = lane & 15, g = lane >> 4;
  const int m0 = blockIdx.x * 64;
  const int arow = lane >> 3, acol = (lane & 7) * 4;   // A staging decode
  float* Aw = S + w * 4608;

  // --- probes: C/D (lane,reg)->(i,j) for mfma_f32_16x16x32_bf16 (exact ints) ---
  int irow[4], jcol[4];
  {
    union { unsigned short u[8]; short8 v; } ar, on;
#pragma unroll
    for (int j = 0; j < 8; ++j) { ar.u[j] = f2bf((float)lrow); on.u[j] = 0x3F80u; }
    f32x4 z = {0.f, 0.f, 0.f, 0.f};
    f32x4 p1 = __builtin_amdgcn_mfma_f32_16x16x32_bf16(ar.v, on.v, z, 0, 0, 0);
    f32x4 p2 = __builtin_amdgcn_mfma_f32_16x16x32_bf16(on.v, ar.v, z, 0, 0, 0);
#pragma unroll
    for (int b = 0; b < 4; ++b) {
      irow[b] = ((int)p1[b]) >> 5;
      jcol[b] = ((int)p2[b]) >> 5;
    }
  }

  f32x4 acc[4][4];   // [row-frag][col-block]
#pragma unroll
  for (int rf = 0; rf < 4; ++rf)
#pragma unroll
    for (int cb = 0; cb < 4; ++cb) acc[rf][cb] = (f32x4){0.f, 0.f, 0.f, 0.f};

  const int boff = lane * 8;
  const int T0 = w * 8;             // wave's k-tiles: T0..T0+7

  f32x4 sreg[8];                    // A staging regs (one tile = 8 KB)
  short8 bhP[4], bmP[4], bhQ[4], bmQ[4];

#define GLOADA(T)                                                                    \
  {                                                                                  \
    _Pragma("unroll")                                                                \
    for (int i = 0; i < 8; ++i)                                                      \
      sreg[i] = *(const f32x4*)(x + (size_t)(m0 + i * 8 + arow) * DM +               \
                                (T) * 32 + acol);                                    \
  }

#define DSWRITE(buf)                                                                 \
  {                                                                                  \
    _Pragma("unroll")                                                                \
    for (int i = 0; i < 8; ++i)                                                      \
      *(f32x4*)(Aw + (buf) * 2304 + (i * 8 + arow) * 36 + acol) = sreg[i];           \
  }

#define LOADB_(T, bh, bm)                                                            \
  {                                                                                  \
    _Pragma("unroll")                                                                \
    for (int cb = 0; cb < 4; ++cb) {                                                 \
      const size_t bo = (size_t)((T) * 4 + cb) * 512 + boff;                         \
      bh[cb] = *(const short8*)(wph + bo);                                           \
      bm[cb] = *(const short8*)(wpm + bo);                                           \
    }                                                                                \
  }

#define FRAG_MFMA(buf, bh, bm)                                                       \
  {                                                                                  \
    _Pragma("unroll")                                                                \
    for (int rf = 0; rf < 4; ++rf) {                                                 \
      f32x4 lo = *(const f32x4*)(Aw + (buf) * 2304 + (rf * 16 + lrow) * 36 + g * 8); \
      f32x4 hi = *(const f32x4*)(Aw + (buf) * 2304 + (rf * 16 + lrow) * 36 + g * 8 + 4); \
      union { unsigned short u[8]; short8 v; } ah, am;                               \
      _Pragma("unroll")                                                              \
      for (int j = 0; j < 8; ++j) {                                                  \
        float v0 = (j < 4) ? lo[j] : hi[j - 4];                                      \
        unsigned short h_ = f2bf(v0);                                                \
        ah.u[j] = h_; am.u[j] = f2bf(v0 - bf2f(h_));                                 \
      }                                                                              \
      _Pragma("unroll")                                                              \
      for (int cb = 0; cb < 4; ++cb) {                                               \
        acc[rf][cb] = __builtin_amdgcn_mfma_f32_16x16x32_bf16(ah.v, bh[cb],          \
                                                              acc[rf][cb], 0, 0, 0); \
        acc[rf][cb] = __builtin_amdgcn_mfma_f32_16x16x32_bf16(am.v, bh[cb],          \
                                                              acc[rf][cb], 0, 0, 0); \
        acc[rf][cb] = __builtin_amdgcn_mfma_f32_16x16x32_bf16(ah.v, bm[cb],          \
                                                              acc[rf][cb], 0, 0, 0); \
      }                                                                              \
    }                                                                                \
  }

  // prologue: stage tile 0, prefetch B(0)
  GLOADA(T0);
  DSWRITE(0);
  LOADB_(T0, bhP, bmP);

#pragma unroll
  for (int t = 0; t < 8; ++t) {
    if (t + 1 < 8) {
      GLOADA(T0 + t + 1);                     // issue next A (coalesced, 8 lines/ld)
      if (t & 1) { LOADB_(T0 + t + 1, bhP, bmP); }   // issue next B
      else       { LOADB_(T0 + t + 1, bhQ, bmQ); }
    }
    if (t & 1) { FRAG_MFMA(1, bhQ, bmQ); }    // compute tile t (LDS + regs)
    else       { FRAG_MFMA(0, bhP, bmP); }
    if (t + 1 < 8) DSWRITE((t + 1) & 1);      // drain A loads under-lapped w/ MFMA
  }

#undef GLOADA
#undef DSWRITE
#undef LOADB_
#undef FRAG_MFMA

  __syncthreads();   // all waves done with A staging before Lt overlay

  // --- per-wave partial logits (probe-measured mapping) ---
#pragma unroll
  for (int rf = 0; rf < 4; ++rf)
#pragma unroll
    for (int cb = 0; cb < 4; ++cb)
#pragma unroll
      for (int b = 0; b < 4; ++b)
        Lt[w][rf * 16 + irow[b]][cb * 16 + jcol[b]] = acc[rf][cb][b];
  __syncthreads();

  // --- fp32 softmax: 4 threads per token (64 tokens), 16 experts each ---
  float pr[16];
  const int tk = tid >> 2, q = tid & 3;
  {
    float st = temp[0];
    if (st < 0.1f) st = 0.1f;
    const float inv_t = 1.0f / st;
    float l[16];
    float mx = -1.0e30f;
#pragma unroll
    for (int j = 0; j < 16; ++j) {
      const int e = q * 16 + j;
      l[j] = (Lt[0][tk][e] + Lt[1][tk][e] + Lt[2][tk][e] + Lt[3][tk][e] + bias[e]) *
             inv_t;
      mx = fmaxf(mx, l[j]);
    }
    mx = fmaxf(mx, __shfl_xor(mx, 1));
    mx = fmaxf(mx, __shfl_xor(mx, 2));
    float p[16], s = 0.0f;
#pragma unroll
    for (int j = 0; j < 16; ++j) { p[j] = __expf(l[j] - mx); s += p[j]; }
    s += __shfl_xor(s, 1);
    s += __shfl_xor(s, 2);
    const float invs = 1.0f / s;
#pragma unroll
    for (int j = 0; j < 16; ++j) pr[j] = p[j] * invs;
  }
  __syncthreads();   // all Lt reads complete before Pt overlay
#pragma unroll
  for (int j = 0; j < 16; ++j) Pt[q * 16 + j][tk] = pr[j];
  __syncthreads();

  // --- expert-major store: 4 threads per expert, 64 tokens contiguous (256B) ---
  {
    const int e = tid >> 2, qq = tid & 3;
    float* dst = probsT + (size_t)e * GS + m0 + qq * 16;
#pragma unroll
    for (int c2 = 0; c2 < 4; ++c2)
      *(float4*)(dst + c2 * 4) = *(const float4*)(&Pt[e][qq * 16 + c2 * 4]);
  }
}

// ------------- cooperative bucket pick from a 256-bin histogram (block-wide) ------
__device__ __forceinline__ void pick_scan(const unsigned* __restrict__ bins,
                                          unsigned r_in, unsigned& bucket,
                                          unsigned& r_out, unsigned* res) {
  __syncthreads();
  const int tid = threadIdx.x;
  if (tid < 64) {
    uint4 b = ((const uint4*)bins)[tid];
    unsigned s3 = b.w, s2 = b.z + s3, s1 = b.y + s2, s0 = b.x + s1;
    unsigned suf = s0;
#pragma unroll
    for (int off = 1; off < 64; off <<= 1) {
      unsigned t = __shfl_down(suf, off);
      if (tid + off < 64) suf += t;
    }
    unsigned above = suf - s0;
    unsigned inc0 = above + s0, inc1 = above + s1, inc2 = above + s2, inc3 = above + s3;
    if (inc3 >= r_in && inc3 - b.w < r_in) { res[0] = 4 * tid + 3; res[1] = r_in - (inc3 - b.w); }
    if (inc2 >= r_in && inc2 - b.z < r_in) { res[0] = 4 * tid + 2; res[1] = r_in - (inc2 - b.z); }
    if (inc1 >= r_in && inc1 - b.y < r_in) { res[0] = 4 * tid + 1; res[1] = r_in - (inc1 - b.y); }
    if (inc0 >= r_in && inc0 - b.x < r_in) { res[0] = 4 * tid + 0; res[1] = r_in - (inc0 - b.x); }
  }
  __syncthreads();
  bucket = res[0];
  r_out = res[1];
}

// ---------------- Kernel 2: pass-0 (top-byte) histogram, full scan ----------------
__global__ __launch_bounds__(256)
void k_hist0(const float* __restrict__ probsT, unsigned* __restrict__ ghist0) {
  __shared__ unsigned h[4][256];
  const int tid = threadIdx.x, wv = tid >> 6;
  const int e = blockIdx.x >> 4;
  const int seg = blockIdx.x & (SEG - 1);
  h[0][tid] = 0; h[1][tid] = 0; h[2][tid] = 0; h[3][tid] = 0;
  __syncthreads();
  const float4* col = (const float4*)(probsT + (size_t)e * GS + seg * SEGLEN);
#pragma unroll
  for (int i = 0; i < SEGLEN / 1024; ++i) {
    float4 v = col[i * 256 + tid];
    atomicAdd(&h[wv][__float_as_uint(v.x) >> 24], 1u);
    atomicAdd(&h[wv][__float_as_uint(v.y) >> 24], 1u);
    atomicAdd(&h[wv][__float_as_uint(v.z) >> 24], 1u);
    atomicAdd(&h[wv][__float_as_uint(v.w) >> 24], 1u);
  }
  __syncthreads();
  unsigned c = h[0][tid] + h[1][tid] + h[2][tid] + h[3][tid];
  if (c) atomicAdd(&ghist0[e * 256 + tid], c);
}

// ---------------- Kernel 3: compact tokens with top-byte >= b0-1 ------------------
__global__ __launch_bounds__(256)
void k_compact(const float* __restrict__ probsT, const unsigned* __restrict__ ghist0,
               unsigned* __restrict__ cCnt, int* __restrict__ cIdx,
               float* __restrict__ cKey) {
  __shared__ unsigned res[2];
  __shared__ unsigned locN, basePos;
  __shared__ int locIdx[2048];
  __shared__ float locKey[2048];
  const int tid = threadIdx.x;
  const int e = blockIdx.x >> 4;
  const int seg = blockIdx.x & (SEG - 1);

  if (tid == 0) locN = 0u;
  unsigned b0, r0;
  pick_scan(ghist0 + e * 256, KSEL, b0, r0, res);
  const unsigned blo = (b0 == 0u) ? 0u : (b0 - 1u);

  const float* col = probsT + (size_t)e * GS + seg * SEGLEN;
  for (int i = 0; i < SEGLEN / 256; ++i) {
    const int t = i * 256 + tid;
    const float p = col[t];
    if ((__float_as_uint(p) >> 24) >= blo) {
      unsigned pos = atomicAdd(&locN, 1u);
      locIdx[pos] = seg * SEGLEN + t;
      locKey[pos] = p;
    }
  }
  __syncthreads();
  if (tid == 0) basePos = locN ? atomicAdd(&cCnt[e], locN) : 0u;
  __syncthreads();
  const unsigned n = locN, bp = basePos;
  for (unsigned i = tid; i < n; i += 256) {
    const unsigned gp = bp + i;
    if (gp < CAP2) {
      cIdx[(size_t)e * CAP2 + gp] = locIdx[i];
      cKey[(size_t)e * CAP2 + gp] = locKey[i];
    }
  }
}

// ---------------- Kernel 4: per-expert radix passes 1-3 + classify ----------------
__global__ __launch_bounds__(256)
void k_select2(const unsigned* __restrict__ ghist0, const unsigned* __restrict__ cCnt,
               const int* __restrict__ cIdx, const float* __restrict__ cKey,
               const float* __restrict__ temp, unsigned* __restrict__ defCnt,
               unsigned* __restrict__ candCnt, int* __restrict__ candIdx,
               float* __restrict__ thrHiA) {
  __shared__ unsigned res[2];
  __shared__ unsigned h[4][256];
  __shared__ unsigned hs[256];
  __shared__ unsigned nd, nc;
  const int tid = threadIdx.x, wv = tid >> 6;
  const int e = blockIdx.x;
  const int cnt = (int)min(cCnt[e], (unsigned)CAP2);

  unsigned b0, r;
  pick_scan(ghist0 + e * 256, KSEL, b0, r, res);
  unsigned pfx = b0 << 24;

  for (int pass = 1; pass < 4; ++pass) {
    const int shift = 24 - 8 * pass;
    const unsigned hm = 0xFFFFFFFFu << (shift + 8);
    for (int i = tid; i < 1024; i += 256) ((unsigned*)h)[i] = 0u;
    __syncthreads();
    for (int i = tid; i < cnt; i += 256) {
      unsigned key = __float_as_uint(cKey[(size_t)e * CAP2 + i]);
      if ((key & hm) == (pfx & hm)) atomicAdd(&h[wv][(key >> shift) & 255], 1u);
    }
    __syncthreads();
    hs[tid] = h[0][tid] + h[1][tid] + h[2][tid] + h[3][tid];
    unsigned b, rn;
    pick_scan(hs, r, b, rn, res);
    pfx |= b << shift;
    r = rn;
  }

  const float thrv = __uint_as_float(pfx);
  float st = temp[0];
  if (st < 0.1f) st = 0.1f;
  const float rel = 2.0e-3f / st;
  const float hi = thrv * (1.0f + rel);
  const float lo = thrv * (1.0f - rel);
  if (tid == 0) thrHiA[e] = hi;

  if (tid == 0) { nd = 0u; nc = 0u; }
  __syncthreads();
  for (int i = tid; i < cnt; i += 256) {
    const float p = cKey[(size_t)e * CAP2 + i];
    const int t = cIdx[(size_t)e * CAP2 + i];
    if (p > hi) {
      atomicAdd(&nd, 1u);
    } else if (p >= lo) {
      unsigned pos = atomicAdd(&nc, 1u);
      if (pos < CAP) candIdx[e * CAP + pos] = t;
    }
  }
  __syncthreads();
  if (tid == 0) {
    defCnt[e] = nd;
    candCnt[e] = min(nc, (unsigned)CAP);
  }
}

// ---------------- Kernel 5: exact fp64 recompute of candidate probabilities -------
__global__ __launch_bounds__(256)
void k_repair(const float* __restrict__ x, const float* __restrict__ w,
              const float* __restrict__ bias, const float* __restrict__ temp,
              const unsigned* __restrict__ candCnt, const int* __restrict__ candIdx,
              double* __restrict__ candKey) {
  __shared__ double red[4][64];
  const int e = blockIdx.x >> 4;
  const int chunk = blockIdx.x & 15;
  const int tid = threadIdx.x;
  const int ee = tid & 63, q = tid >> 6;
  const int cnt = (int)min(candCnt[e], (unsigned)CAP);

  double st = (double)temp[0];
  if (st < 0.1) st = 0.1;
  const double inv_t = 1.0 / st;

  for (int i = chunk; i < cnt; i += 16) {
    const int t = candIdx[e * CAP + i];
    const float* xr = x + (size_t)t * DM;
    double s0 = 0.0, s1 = 0.0, s2 = 0.0, s3 = 0.0;
    const int kb = q * 256;
    for (int k = kb; k < kb + 256; k += 4) {
      s0 += (double)xr[k + 0] * (double)w[(size_t)(k + 0) * NE + ee];
      s1 += (double)xr[k + 1] * (double)w[(size_t)(k + 1) * NE + ee];
      s2 += (double)xr[k + 2] * (double)w[(size_t)(k + 2) * NE + ee];
      s3 += (double)xr[k + 3] * (double)w[(size_t)(k + 3) * NE + ee];
    }
    red[q][ee] = (s0 + s1) + (s2 + s3);
    __syncthreads();
    if (tid < 64) {
      double l = (red[0][tid] + red[1][tid] + red[2][tid] + red[3][tid] +
                  (double)bias[tid]) * inv_t;
      double m = l;
#pragma unroll
      for (int off = 1; off < 64; off <<= 1) m = fmax(m, __shfl_xor(m, off));
      double ex = exp(l - m);
      double ss = ex;
#pragma unroll
      for (int off = 1; off < 64; off <<= 1) ss += __shfl_xor(ss, off);
      if (tid == e) candKey[e * CAP + i] = ex / ss;
    }
    __syncthreads();
  }
}

// ---------------- Kernel 6: dense mask scatter (definite region) + loss -----------
__global__ __launch_bounds__(256)
void k_scatter(const float* __restrict__ probsT, const float* __restrict__ thrHiA,
               float* __restrict__ out) {
  const int gid = blockIdx.x * 256 + threadIdx.x;
  const int base = gid * 4;
  const int e = base >> 15;
  float4 p = *(const float4*)(probsT + (size_t)base);
  const float hi = thrHiA[e];
  float pv[4] = {p.x, p.y, p.z, p.w};
  float mk[4], wt[4];
#pragma unroll
  for (int c = 0; c < 4; ++c) {
    bool sel = pv[c] > hi;
    mk[c] = sel ? 1.0f : 0.0f;
    wt[c] = sel ? pv[c] : 0.0f;
  }
  *(float4*)(out + (size_t)base) = make_float4(mk[0], mk[1], mk[2], mk[3]);
  *(float4*)(out + (size_t)MASK_ELEMS + base) = make_float4(wt[0], wt[1], wt[2], wt[3]);
  if (gid == 0) out[2 * (size_t)MASK_ELEMS] = 0.0f;
}

// ---------------- Kernel 7: rank candidates, patch selected into output -----------
__global__ __launch_bounds__(256)
void k_finish(const unsigned* __restrict__ defCnt, const unsigned* __restrict__ candCnt,
              const int* __restrict__ candIdx, const double* __restrict__ candKey,
              const float* __restrict__ probsT, float* __restrict__ out) {
  __shared__ double kd[CAP];
  __shared__ int ti[CAP];
  const int e = blockIdx.x, tid = threadIdx.x;
  const int cnt = (int)min(candCnt[e], (unsigned)CAP);
  const int need = KSEL - (int)defCnt[e];

  for (int i = tid; i < cnt; i += 256) {
    kd[i] = candKey[e * CAP + i];
    ti[i] = candIdx[e * CAP + i];
  }
  __syncthreads();
  for (int i = tid; i < cnt; i += 256) {
    const double ki = kd[i];
    const int tii = ti[i];
    int rank = 0;
    for (int j = 0; j < cnt; ++j)
      rank += (kd[j] > ki) || (kd[j] == ki && ti[j] < tii);
    if (rank < need) {
      out[(size_t)e * GS + tii] = 1.0f;
      out[(size_t)MASK_ELEMS + (size_t)e * GS + tii] = probsT[(size_t)e * GS + tii];
    }
  }
}

extern "C" void kernel_launch(void* const* d_in, const int* in_sizes, int n_in,
                              void* d_out, int out_size, void* d_ws, size_t ws_size,
                              hipStream_t stream) {
  const float* x    = (const float*)d_in[0];
  const float* gw   = (const float*)d_in[1];
  const float* gb   = (const float*)d_in[2];
  const float* temp = (const float*)d_in[3];

  float* probsT    = (float*)d_ws;                                        // 8MB
  unsigned* ghist0 = (unsigned*)((char*)d_ws + (size_t)MASK_ELEMS * 4);   // 64KB
  unsigned* cCnt   = ghist0 + NE * 256;                                   // 256B
  unsigned* defCnt = cCnt + NE;                                           // 256B
  unsigned* candCnt = defCnt + NE;                                        // 256B
  float* thrHiA    = (float*)(candCnt + NE);                              // 256B
  int* candIdx     = (int*)(thrHiA + NE);                                 // 512KB
  double* candKey  = (double*)(candIdx + NE * CAP);                       // 1MB
  int* cIdx        = (int*)(candKey + NE * CAP);                          // 4MB
  float* cKey      = (float*)(cIdx + (size_t)NE * CAP2);                  // 4MB
  unsigned short* wph = (unsigned short*)(cKey + (size_t)NE * CAP2);      // 128KB
  unsigned short* wpm = wph + DM * NE;                                    // 128KB

  k_split<<<DM * NE / 256, 256, 0, stream>>>(gw, wph, wpm, ghist0);
  k_gemm_softmax<<<GS / 64, 256, 0, stream>>>(x, wph, wpm, gb, temp, probsT);
  k_hist0<<<NE * SEG, 256, 0, stream>>>(probsT, ghist0);
  k_compact<<<NE * SEG, 256, 0, stream>>>(probsT, ghist0, cCnt, cIdx, cKey);
  k_select2<<<NE, 256, 0, stream>>>(ghist0, cCnt, cIdx, cKey, temp, defCnt,
                                    candCnt, candIdx, thrHiA);
  k_repair<<<NE * 16, 256, 0, stream>>>(x, gw, gb, temp, candCnt, candIdx, candKey);
  k_scatter<<<MASK_ELEMS / 1024, 256, 0, stream>>>(probsT, thrHiA, (float*)d_out);
  k_finish<<<NE, 256, 0, stream>>>(defCnt, candCnt, candIdx, candKey,
                                   probsT, (float*)d_out);
}